// Round 1
// baseline (502.005 us; speedup 1.0000x reference)
//
#include <hip/hip_runtime.h>
#include <math.h>

#define NB 8
#define NC 512
#define NN 2048

static constexpr int TM = 64, TN = 64, KB = 16;

__device__ __forceinline__ unsigned f2mono(float v) {
    unsigned b = __float_as_uint(v);
    return (b & 0x80000000u) ? ~b : (b | 0x80000000u);
}

// ---------------- Kernel 1: scores GEMM + fused gumbel argmax ----------------
extern "C" __global__ __launch_bounds__(256)
void scores_argmax(const float* __restrict__ srcE,
                   const float* __restrict__ tgtE,
                   const float* __restrict__ gum,
                   const float* __restrict__ temp,
                   unsigned long long* __restrict__ best)
{
    __shared__ __align__(16) float As[KB][TM];
    __shared__ __align__(16) float Bs[KB][TN];
    const int b  = blockIdx.z;
    const int n0 = blockIdx.x * TM;
    const int m0 = blockIdx.y * TN;
    const int tid = threadIdx.x;
    const int tx = tid & 15, ty = tid >> 4;

    const int t4 = tid * 4;
    const int lk = t4 >> 6;   // 0..15  (k-row within tile)
    const int lc = t4 & 63;   // col within tile

    const float* Ag = srcE + ((size_t)b * NC) * NN + n0 + lc;
    const float* Bg = tgtE + ((size_t)b * NC) * NN + m0 + lc;

    float acc[4][4] = {};
    for (int k0 = 0; k0 < NC; k0 += KB) {
        const float4 a4 = *(const float4*)(Ag + (size_t)(k0 + lk) * NN);
        const float4 b4 = *(const float4*)(Bg + (size_t)(k0 + lk) * NN);
        __syncthreads();
        *(float4*)&As[lk][lc] = a4;
        *(float4*)&Bs[lk][lc] = b4;
        __syncthreads();
#pragma unroll
        for (int k = 0; k < KB; ++k) {
            const float4 av = *(const float4*)&As[k][ty * 4];
            const float4 bv = *(const float4*)&Bs[k][tx * 4];
            const float aa[4] = {av.x, av.y, av.z, av.w};
            const float bb[4] = {bv.x, bv.y, bv.z, bv.w};
#pragma unroll
            for (int i = 0; i < 4; ++i)
#pragma unroll
                for (int j = 0; j < 4; ++j)
                    acc[i][j] = fmaf(aa[i], bb[j], acc[i][j]);
        }
    }

    const float SCL = 0.044194173824159216f;  // 1/sqrt(512)
    const float tau = temp[b];
#pragma unroll
    for (int i = 0; i < 4; ++i) {
        const int n = n0 + ty * 4 + i;
        const float4 u4 = *(const float4*)(gum + ((size_t)(b * NN + n)) * NN + m0 + tx * 4);
        const float uu[4] = {u4.x, u4.y, u4.z, u4.w};
        unsigned long long bp = 0ULL;
#pragma unroll
        for (int j = 0; j < 4; ++j) {
            float u = fminf(fmaxf(uu[j], 1e-6f), 1.0f - 1e-6f);
            float g = -logf(-logf(u));
            float val = (acc[i][j] * SCL + g) / tau;
            const int m = m0 + tx * 4 + j;
            unsigned long long p =
                ((unsigned long long)f2mono(val) << 32) | (unsigned)(NN - 1 - m);
            bp = (p > bp) ? p : bp;
        }
        // reduce across the 16 lanes (tx group) sharing this row
#pragma unroll
        for (int off = 8; off > 0; off >>= 1) {
            unsigned long long o = __shfl_xor(bp, off, 16);
            bp = (o > bp) ? o : bp;
        }
        if (tx == 0) atomicMax(&best[(size_t)b * NN + n], bp);
    }
}

// ---------------- Kernel 2: gather + covariance + 3x3 SVD + R,t ----------------
__device__ __forceinline__ double det3(const double M[3][3]) {
    return M[0][0] * (M[1][1] * M[2][2] - M[1][2] * M[2][1])
         - M[0][1] * (M[1][0] * M[2][2] - M[1][2] * M[2][0])
         + M[0][2] * (M[1][0] * M[2][1] - M[1][1] * M[2][0]);
}

extern "C" __global__ __launch_bounds__(256)
void assemble(const float* __restrict__ src, const float* __restrict__ tgt,
              const unsigned long long* __restrict__ best, float* __restrict__ out)
{
    const int b = blockIdx.x;
    const int tid = threadIdx.x;
    float P[9] = {}, Ss[3] = {}, Sc[3] = {};
    for (int n = tid; n < NN; n += 256) {
        const int m = (NN - 1) - (int)(unsigned)(best[(size_t)b * NN + n] & 0xffffffffu);
        float sv[3], cv[3];
#pragma unroll
        for (int c = 0; c < 3; ++c) {
            sv[c] = src[((size_t)b * 3 + c) * NN + n];
            cv[c] = tgt[((size_t)b * 3 + c) * NN + m];
            Ss[c] += sv[c];
            Sc[c] += cv[c];
        }
#pragma unroll
        for (int c = 0; c < 3; ++c)
#pragma unroll
            for (int d = 0; d < 3; ++d)
                P[c * 3 + d] = fmaf(sv[c], cv[d], P[c * 3 + d]);
    }

    float vals[15];
#pragma unroll
    for (int i = 0; i < 9; ++i) vals[i] = P[i];
#pragma unroll
    for (int i = 0; i < 3; ++i) { vals[9 + i] = Ss[i]; vals[12 + i] = Sc[i]; }

    __shared__ float red[4][15];
    const int lane = tid & 63, wv = tid >> 6;
#pragma unroll
    for (int i = 0; i < 15; ++i) {
        float v = vals[i];
        for (int off = 32; off > 0; off >>= 1) v += __shfl_down(v, off, 64);
        if (lane == 0) red[wv][i] = v;
    }
    __syncthreads();

    if (tid == 0) {
        double tot[15];
        for (int i = 0; i < 15; ++i)
            tot[i] = (double)red[0][i] + red[1][i] + red[2][i] + red[3][i];
        double smean[3], cmean[3], H[3][3];
        for (int c = 0; c < 3; ++c) { smean[c] = tot[9 + c] / NN; cmean[c] = tot[12 + c] / NN; }
        for (int c = 0; c < 3; ++c)
            for (int d = 0; d < 3; ++d)
                H[c][d] = tot[c * 3 + d] - tot[9 + c] * tot[12 + d] / NN;

        // one-sided Jacobi SVD on columns of W: H = U S V^T
        double W[3][3], V[3][3];
        for (int i = 0; i < 3; ++i)
            for (int j = 0; j < 3; ++j) { W[i][j] = H[i][j]; V[i][j] = (i == j) ? 1.0 : 0.0; }
        for (int sweep = 0; sweep < 60; ++sweep) {
            double offsum = 0.0;
            for (int p = 0; p < 2; ++p)
                for (int q = p + 1; q < 3; ++q) {
                    double al = 0, be = 0, ga = 0;
                    for (int r = 0; r < 3; ++r) {
                        al += W[r][p] * W[r][p];
                        be += W[r][q] * W[r][q];
                        ga += W[r][p] * W[r][q];
                    }
                    offsum += fabs(ga);
                    if (fabs(ga) <= 1e-15 * sqrt(al * be)) continue;
                    double zeta = (be - al) / (2.0 * ga);
                    double t = copysign(1.0, zeta) / (fabs(zeta) + sqrt(1.0 + zeta * zeta));
                    double c = 1.0 / sqrt(1.0 + t * t), s = c * t;
                    for (int r = 0; r < 3; ++r) {
                        double wp = W[r][p], wq = W[r][q];
                        W[r][p] = c * wp - s * wq;
                        W[r][q] = s * wp + c * wq;
                        double vp = V[r][p], vq = V[r][q];
                        V[r][p] = c * vp - s * vq;
                        V[r][q] = s * vp + c * vq;
                    }
                }
            if (offsum < 1e-13) break;
        }
        double S[3];
        for (int i = 0; i < 3; ++i)
            S[i] = sqrt(W[0][i] * W[0][i] + W[1][i] * W[1][i] + W[2][i] * W[2][i]);
        // sort descending (columns of W and V follow)
        for (int i = 0; i < 2; ++i) {
            int mx = i;
            for (int j = i + 1; j < 3; ++j) if (S[j] > S[mx]) mx = j;
            if (mx != i) {
                double tS = S[i]; S[i] = S[mx]; S[mx] = tS;
                for (int r = 0; r < 3; ++r) {
                    double tw = W[r][i]; W[r][i] = W[r][mx]; W[r][mx] = tw;
                    double tv = V[r][i]; V[r][i] = V[r][mx]; V[r][mx] = tv;
                }
            }
        }
        double U[3][3];
        for (int i = 0; i < 3; ++i) {
            if (S[i] > 1e-12 * S[0] && S[i] > 0.0) {
                for (int r = 0; r < 3; ++r) U[r][i] = W[r][i] / S[i];
            } else {
                // only meaningful for the smallest column: cross of the first two
                double ux = U[1][0] * U[2][1] - U[2][0] * U[1][1];
                double uy = U[2][0] * U[0][1] - U[0][0] * U[2][1];
                double uz = U[0][0] * U[1][1] - U[1][0] * U[0][1];
                double nr = sqrt(ux * ux + uy * uy + uz * uz);
                if (nr < 1e-30) { ux = 1.0; uy = 0.0; uz = 0.0; nr = 1.0; }
                U[0][i] = ux / nr; U[1][i] = uy / nr; U[2][i] = uz / nr;
            }
        }
        // r = V U^T ; det ; R = V diag(1,1,det) U^T ; t = -R smean + cmean
        double r_[3][3];
        for (int i = 0; i < 3; ++i)
            for (int j = 0; j < 3; ++j)
                r_[i][j] = V[i][0] * U[j][0] + V[i][1] * U[j][1] + V[i][2] * U[j][2];
        double det = det3(r_);
        double R[3][3];
        for (int i = 0; i < 3; ++i)
            for (int j = 0; j < 3; ++j)
                R[i][j] = V[i][0] * U[j][0] + V[i][1] * U[j][1] + det * V[i][2] * U[j][2];
        double t_[3];
        for (int i = 0; i < 3; ++i)
            t_[i] = -(R[i][0] * smean[0] + R[i][1] * smean[1] + R[i][2] * smean[2]) + cmean[i];

        for (int i = 0; i < 3; ++i)
            for (int j = 0; j < 3; ++j)
                out[b * 9 + i * 3 + j] = (float)R[i][j];
        for (int i = 0; i < 3; ++i) out[NB * 9 + b * 3 + i] = (float)t_[i];
    }
}

// ---------------- launcher ----------------
extern "C" void kernel_launch(void* const* d_in, const int* in_sizes, int n_in,
                              void* d_out, int out_size, void* d_ws, size_t ws_size,
                              hipStream_t stream)
{
    const float* srcE = (const float*)d_in[0];
    const float* tgtE = (const float*)d_in[1];
    const float* src  = (const float*)d_in[2];
    const float* tgt  = (const float*)d_in[3];
    const float* temp = (const float*)d_in[4];
    const float* gum  = (const float*)d_in[5];
    float* out = (float*)d_out;
    unsigned long long* best = (unsigned long long*)d_ws;

    // zero the argmax buffer every call (monotonic key encoding makes 0 = -inf)
    hipMemsetAsync(best, 0, (size_t)NB * NN * sizeof(unsigned long long), stream);

    dim3 grid(NN / TM, NN / TN, NB);
    scores_argmax<<<grid, 256, 0, stream>>>(srcE, tgtE, gum, temp, best);
    assemble<<<NB, 256, 0, stream>>>(src, tgt, best, out);
}